// Round 1
// baseline (837.470 us; speedup 1.0000x reference)
//
#include <hip/hip_runtime.h>

#define B_ 8
#define N_ 4096
#define K_ 32
#define C_ 64
#define CIN_ 67
#define R2_ 0.0225f

// ---------------------------------------------------------------------------
// Ball query: one wave (64 lanes) per query point. Scans candidate indices in
// order, collects first K_ within radius via ballot+rank, pads with first.
// fp contract OFF so d2 matches numpy's non-FMA arithmetic at the boundary.
// ---------------------------------------------------------------------------
__global__ __launch_bounds__(256) void ball_query_kernel(
    const float* __restrict__ p, int* __restrict__ idx)
{
#pragma clang fp contract(off)
    const int lane = threadIdx.x & 63;
    const int q = (blockIdx.x * blockDim.x + threadIdx.x) >> 6;  // global wave id
    const int b = q >> 12;           // N_ = 4096
    const int n = q & (N_ - 1);
    const float* pb = p + (size_t)b * N_ * 3;
    const float qx = pb[n * 3 + 0];
    const float qy = pb[n * 3 + 1];
    const float qz = pb[n * 3 + 2];
    const float sqn = (qx * qx + qy * qy) + qz * qz;
    int* out = idx + (size_t)q * K_;
    int count = 0;
    int first = -1;
    for (int base = 0; base < N_; base += 64) {
        const int m = base + lane;
        const float mx = pb[m * 3 + 0];
        const float my = pb[m * 3 + 1];
        const float mz = pb[m * 3 + 2];
        const float sqm = (mx * mx + my * my) + mz * mz;
        const float dot = (qx * mx + qy * my) + qz * mz;
        const float d2 = (sqn + sqm) - 2.0f * dot;
        const bool within = (d2 <= R2_);
        const unsigned long long mask = __ballot(within);
        if (mask) {
            if (first < 0) first = base + __builtin_ctzll(mask);
            if (within) {
                const int pos = count + __popcll(mask & ((1ull << lane) - 1ull));
                if (pos < K_) out[pos] = m;
            }
            count += __popcll(mask);
            if (count >= K_) break;
        }
    }
    // pad (count >= 1 always: the query point itself is within)
    for (int pos = count + lane; pos < K_; pos += 64) out[pos] = first;
}

// ---------------------------------------------------------------------------
// Fused per-point kernel. Block = 256 threads; thread t -> channel c = t>>2,
// k-slice ks = t&3 (handles k = ks*8 .. ks*8+7). Block processes 16 points.
// Weights w_attn/w1/w2 staged in LDS once per block; fj_cat tile (67x32,
// padded to 68x36 for alignment + zero-pad row) gathered per point.
// ---------------------------------------------------------------------------
__device__ inline void fma8(float (&acc)[8], const float w, const float4& a, const float4& b)
{
    acc[0] += w * a.x; acc[1] += w * a.y; acc[2] += w * a.z; acc[3] += w * a.w;
    acc[4] += w * b.x; acc[5] += w * b.y; acc[6] += w * b.z; acc[7] += w * b.w;
}

__global__ __launch_bounds__(256) void lpa_fused_kernel(
    const float* __restrict__ p, const float* __restrict__ f,
    const float* __restrict__ w_attn, const float* __restrict__ b_attn,
    const float* __restrict__ w1, const float* __restrict__ b1,
    const float* __restrict__ w2, const float* __restrict__ b2,
    const float* __restrict__ wf1, const float* __restrict__ bf1,
    const float* __restrict__ wf2, const float* __restrict__ bf2,
    const int* __restrict__ idx, float* __restrict__ out)
{
    __shared__ __align__(16) float smem[17680];
    __shared__ int s_idx[K_];
    float* s_wa  = smem;           // 64*68 = 4352 (row pad: entry 67 zeroed)
    float* s_w1  = smem + 4352;    // 64*68
    float* s_w2  = smem + 8704;    // 64*64 = 4096
    float* s_fj  = smem + 12800;   // 68*36 = 2448 (rows 0..66 data, row 67 zero)
    float* s_y1  = smem + 15248;   // 64*36 = 2304
    float* s_vec = smem + 17552;   // 64 (fout / identity)
    float* s_h   = smem + 17616;   // 64 (FFN hidden)

    const int t  = threadIdx.x;
    const int c  = t >> 2;
    const int ks = t & 3;

    // ---- stage weights into LDS (once per block) ----
    for (int e = t; e < 64 * 68; e += 256) {
        const int r = e / 68, i = e - r * 68;
        s_wa[e] = (i < CIN_) ? w_attn[r * CIN_ + i] : 0.0f;
        s_w1[e] = (i < CIN_) ? w1[r * CIN_ + i] : 0.0f;
    }
    for (int e = t; e < 64 * 64; e += 256) s_w2[e] = w2[e];
    for (int e = t; e < 36; e += 256) s_fj[67 * 36 + e] = 0.0f;  // zero pad row

    const float bav  = b_attn[c];
    const float b1v  = b1[c];
    const float b2v  = b2[c];
    const float bf1v = bf1[c];
    const float bf2v = bf2[c];
    __syncthreads();

    const int pt0 = blockIdx.x * 16;
    for (int it = 0; it < 16; ++it) {
        const int pt = pt0 + it;
        const int b = pt >> 12;
        const int n = pt & (N_ - 1);

        if (t < K_) s_idx[t] = idx[(size_t)pt * K_ + t];
        __syncthreads();

        const float* pb = p + (size_t)b * N_ * 3;
        const float px = pb[n * 3 + 0], py = pb[n * 3 + 1], pz = pb[n * 3 + 2];

        // ---- gather fj_cat tile: rows 0..2 = dp, rows 3..66 = f[.,c,idx] ----
        for (int e = t; e < CIN_ * K_; e += 256) {
            const int row = e >> 5, k = e & 31;
            const int j = s_idx[k];
            float v;
            if (row < 3) {
                const float qc = (row == 0) ? px : (row == 1) ? py : pz;
                v = pb[j * 3 + row] - qc;
            } else {
                v = f[((size_t)b * C_ + (row - 3)) * N_ + j];
            }
            s_fj[row * 36 + k] = v;
        }
        __syncthreads();

        // ---- attn + conv1 (shared fj reads), 67(+1 pad) input rows ----
        float accA[8] = {0, 0, 0, 0, 0, 0, 0, 0};
        float acc1[8] = {0, 0, 0, 0, 0, 0, 0, 0};
        const float4* wa4 = (const float4*)(s_wa + c * 68);
        const float4* w14 = (const float4*)(s_w1 + c * 68);
        for (int ii = 0; ii < 17; ++ii) {
            const float4 wa = wa4[ii];
            const float4 wb = w14[ii];
            #pragma unroll
            for (int s = 0; s < 4; ++s) {
                const int i = ii * 4 + s;
                const float4 f0 = *(const float4*)(s_fj + i * 36 + ks * 8);
                const float4 f1 = *(const float4*)(s_fj + i * 36 + ks * 8 + 4);
                const float wav = (s == 0) ? wa.x : (s == 1) ? wa.y : (s == 2) ? wa.z : wa.w;
                const float w1s = (s == 0) ? wb.x : (s == 1) ? wb.y : (s == 2) ? wb.z : wb.w;
                fma8(accA, wav, f0, f1);
                fma8(acc1, w1s, f0, f1);
            }
        }

        // ---- y1 = relu(conv1 + b1) -> LDS for conv2 ----
        {
            float4 y0, y1v;
            y0.x  = fmaxf(acc1[0] + b1v, 0.0f);
            y0.y  = fmaxf(acc1[1] + b1v, 0.0f);
            y0.z  = fmaxf(acc1[2] + b1v, 0.0f);
            y0.w  = fmaxf(acc1[3] + b1v, 0.0f);
            y1v.x = fmaxf(acc1[4] + b1v, 0.0f);
            y1v.y = fmaxf(acc1[5] + b1v, 0.0f);
            y1v.z = fmaxf(acc1[6] + b1v, 0.0f);
            y1v.w = fmaxf(acc1[7] + b1v, 0.0f);
            *(float4*)(s_y1 + c * 36 + ks * 8)     = y0;
            *(float4*)(s_y1 + c * 36 + ks * 8 + 4) = y1v;
        }
        __syncthreads();

        // ---- conv2: x = w2 @ y1 + b2 ----
        float accX[8] = {0, 0, 0, 0, 0, 0, 0, 0};
        const float4* w24 = (const float4*)(s_w2 + c * 64);
        for (int ii = 0; ii < 16; ++ii) {
            const float4 w = w24[ii];
            #pragma unroll
            for (int s = 0; s < 4; ++s) {
                const int i = ii * 4 + s;
                const float4 q0 = *(const float4*)(s_y1 + i * 36 + ks * 8);
                const float4 q1 = *(const float4*)(s_y1 + i * 36 + ks * 8 + 4);
                const float wv = (s == 0) ? w.x : (s == 1) ? w.y : (s == 2) ? w.z : w.w;
                fma8(accX, wv, q0, q1);
            }
        }

        // ---- softmax over K per channel + weighted sum (4-lane reduce) ----
        float av[8];
        #pragma unroll
        for (int j = 0; j < 8; ++j) av[j] = accA[j] + bav;
        float mx = av[0];
        #pragma unroll
        for (int j = 1; j < 8; ++j) mx = fmaxf(mx, av[j]);
        mx = fmaxf(mx, __shfl_xor(mx, 1));
        mx = fmaxf(mx, __shfl_xor(mx, 2));
        float se = 0.0f, sw = 0.0f;
        #pragma unroll
        for (int j = 0; j < 8; ++j) {
            const float e = __expf(av[j] - mx);
            se += e;
            sw += e * (accX[j] + b2v);
        }
        se += __shfl_xor(se, 1); se += __shfl_xor(se, 2);
        sw += __shfl_xor(sw, 1); sw += __shfl_xor(sw, 2);

        const float fres = f[((size_t)b * C_ + c) * N_ + n];
        const float fo = fmaxf(sw / se + fres, 0.0f);
        if (ks == 0) s_vec[c] = fo;
        __syncthreads();

        // ---- FFN layer 1: h = relu(wf1 @ fout + bf1) ----
        float acc = 0.0f;
        {
            const float4* wr = (const float4*)(wf1 + c * 64 + ks * 16);
            const float4* vr = (const float4*)(s_vec + ks * 16);
            #pragma unroll
            for (int ii = 0; ii < 4; ++ii) {
                const float4 w = wr[ii];
                const float4 v = vr[ii];
                acc += w.x * v.x + w.y * v.y + w.z * v.z + w.w * v.w;
            }
        }
        acc += __shfl_xor(acc, 1); acc += __shfl_xor(acc, 2);
        const float h = fmaxf(acc + bf1v, 0.0f);
        if (ks == 0) s_h[c] = h;
        __syncthreads();

        // ---- FFN layer 2 + residual + relu, write out ----
        float acc2 = 0.0f;
        {
            const float4* wr = (const float4*)(wf2 + c * 64 + ks * 16);
            const float4* vr = (const float4*)(s_h + ks * 16);
            #pragma unroll
            for (int ii = 0; ii < 4; ++ii) {
                const float4 w = wr[ii];
                const float4 v = vr[ii];
                acc2 += w.x * v.x + w.y * v.y + w.z * v.z + w.w * v.w;
            }
        }
        acc2 += __shfl_xor(acc2, 1); acc2 += __shfl_xor(acc2, 2);
        if (ks == 0) {
            const float o = fmaxf(acc2 + bf2v + s_vec[c], 0.0f);
            out[((size_t)b * C_ + c) * N_ + n] = o;
        }
        __syncthreads();
    }
}

extern "C" void kernel_launch(void* const* d_in, const int* in_sizes, int n_in,
                              void* d_out, int out_size, void* d_ws, size_t ws_size,
                              hipStream_t stream)
{
    const float* p      = (const float*)d_in[0];
    const float* f      = (const float*)d_in[1];
    const float* w_attn = (const float*)d_in[2];
    const float* b_attn = (const float*)d_in[3];
    const float* w1     = (const float*)d_in[4];
    const float* b1     = (const float*)d_in[5];
    const float* w2     = (const float*)d_in[6];
    const float* b2     = (const float*)d_in[7];
    const float* wf1    = (const float*)d_in[8];
    const float* bf1    = (const float*)d_in[9];
    const float* wf2    = (const float*)d_in[10];
    const float* bf2    = (const float*)d_in[11];
    float* out = (float*)d_out;
    int* idx = (int*)d_ws;  // B*N*K int32 = 4 MB scratch

    // Output 0: p passthrough (B*N*3 floats)
    hipMemcpyAsync(out, p, (size_t)B_ * N_ * 3 * sizeof(float),
                   hipMemcpyDeviceToDevice, stream);

    // Ball query: 32768 waves, 4 waves/block
    ball_query_kernel<<<(B_ * N_) / 4, 256, 0, stream>>>(p, idx);

    // Fused attention-MLP: 16 points per 256-thread block
    lpa_fused_kernel<<<(B_ * N_) / 16, 256, 0, stream>>>(
        p, f, w_attn, b_attn, w1, b1, w2, b2, wf1, bf1, wf2, bf2,
        idx, out + (size_t)B_ * N_ * 3);
}

// Round 2
// 318.695 us; speedup vs baseline: 2.6278x; 2.6278x over previous
//
#include <hip/hip_runtime.h>

#define B_ 8
#define N_ 4096
#define K_ 32
#define C_ 64
#define CIN_ 67
#define R2_ 0.0225f

#define SFJ 104   // s_fj row stride in shorts (208 B: 16B-aligned, 2-way banks max)
#define SY1 72    // s_y1 row stride in shorts (144 B)
#define PTS 4     // points per block-iteration
#define ITERS 4   // iterations per block

typedef short short8v __attribute__((ext_vector_type(8)));
typedef short short4v __attribute__((ext_vector_type(4)));
typedef float floatx4 __attribute__((ext_vector_type(4)));

__device__ __forceinline__ short f2bf(float x) {
    unsigned u = __float_as_uint(x);
    u += 0x7fffu + ((u >> 16) & 1u);       // round-to-nearest-even
    return (short)(u >> 16);
}

// ---------------------------------------------------------------------------
// Ball query: one wave per query point (unchanged from R1 — validated).
// ---------------------------------------------------------------------------
__global__ __launch_bounds__(256) void ball_query_kernel(
    const float* __restrict__ p, int* __restrict__ idx)
{
#pragma clang fp contract(off)
    const int lane = threadIdx.x & 63;
    const int q = (blockIdx.x * blockDim.x + threadIdx.x) >> 6;
    const int b = q >> 12;
    const int n = q & (N_ - 1);
    const float* pb = p + (size_t)b * N_ * 3;
    const float qx = pb[n * 3 + 0];
    const float qy = pb[n * 3 + 1];
    const float qz = pb[n * 3 + 2];
    const float sqn = (qx * qx + qy * qy) + qz * qz;
    int* out = idx + (size_t)q * K_;
    int count = 0;
    int first = -1;
    for (int base = 0; base < N_; base += 64) {
        const int m = base + lane;
        const float mx = pb[m * 3 + 0];
        const float my = pb[m * 3 + 1];
        const float mz = pb[m * 3 + 2];
        const float sqm = (mx * mx + my * my) + mz * mz;
        const float dot = (qx * mx + qy * my) + qz * mz;
        const float d2 = (sqn + sqm) - 2.0f * dot;
        const bool within = (d2 <= R2_);
        const unsigned long long mask = __ballot(within);
        if (mask) {
            if (first < 0) first = base + __builtin_ctzll(mask);
            if (within) {
                const int pos = count + __popcll(mask & ((1ull << lane) - 1ull));
                if (pos < K_) out[pos] = m;
            }
            count += __popcll(mask);
            if (count >= K_) break;
        }
    }
    for (int pos = count + lane; pos < K_; pos += 64) out[pos] = first;
}

// ---------------------------------------------------------------------------
// Transpose + bf16-convert f[b][c][n] -> ftb[b][n][c] so the gather can do
// coalesced 16B loads of 8 channels. 512 blocks x 256 threads.
// ---------------------------------------------------------------------------
__global__ __launch_bounds__(256) void transpose_f_kernel(
    const float* __restrict__ f, unsigned short* __restrict__ ftb)
{
    __shared__ short tile[64 * 72];
    const int t = threadIdx.x;
    const int b = blockIdx.x >> 6;
    const int n0 = (blockIdx.x & 63) * 64;
    const int nn4 = t & 15, ch = t >> 4;
    for (int cc = 0; cc < 4; ++cc) {
        const int c = cc * 16 + ch;
        const float4 v = *(const float4*)&f[((size_t)(b * 64 + c)) * N_ + n0 + nn4 * 4];
        tile[(nn4 * 4 + 0) * 72 + c] = f2bf(v.x);
        tile[(nn4 * 4 + 1) * 72 + c] = f2bf(v.y);
        tile[(nn4 * 4 + 2) * 72 + c] = f2bf(v.z);
        tile[(nn4 * 4 + 3) * 72 + c] = f2bf(v.w);
    }
    __syncthreads();
    const int nn = t >> 2, cb = (t & 3) * 16;
    uint4* dst = (uint4*)&ftb[((size_t)(b * N_ + n0 + nn)) * 64 + cb];
    const uint4* src = (const uint4*)&tile[nn * 72 + cb];
    dst[0] = src[0];
    dst[1] = src[1];
}

// ---------------------------------------------------------------------------
// Fused MFMA kernel. Block = 4 waves. Wave mb owns output channels
// [mb*16, mb*16+16). Per iteration: 4 points -> 128 MFMA columns (8 N-tiles).
// Input rows permuted: i'=0..63 f-channels, i'=64..66 dp, 67..95 zero.
// Weight A-frags (permuted to match) live in registers for the whole block.
// ---------------------------------------------------------------------------
__global__ __launch_bounds__(256, 3) void lpa_mfma_kernel(
    const float* __restrict__ p, const float* __restrict__ f,
    const unsigned short* __restrict__ ftb,
    const float* __restrict__ w_attn, const float* __restrict__ b_attn,
    const float* __restrict__ w1, const float* __restrict__ b1,
    const float* __restrict__ w2, const float* __restrict__ b2,
    const float* __restrict__ wf1, const float* __restrict__ bf1,
    const float* __restrict__ wf2, const float* __restrict__ bf2,
    const int* __restrict__ idx, float* __restrict__ out)
{
    __shared__ short s_fj[128 * SFJ];   // 26624 B
    __shared__ short s_y1[128 * SY1];   // 18432 B
    __shared__ float s_vec[PTS * 64];
    __shared__ float s_h[PTS * 64];

    const int t = threadIdx.x;
    const int lane = t & 63;
    const int mb = t >> 6;
    const int l15 = lane & 15;
    const int quad = lane >> 4;

    // ---- weight A-fragments in registers (once per block) ----
    short8v wa_f[3], w1_f[3], w2_f[2];
    {
        const int cm = mb * 16 + l15;
        #pragma unroll
        for (int ks = 0; ks < 3; ++ks) {
            short8v a, bq;
            #pragma unroll
            for (int j = 0; j < 8; ++j) {
                const int ip = ks * 32 + quad * 8 + j;   // permuted i'
                float va = 0.0f, vb = 0.0f;
                if (ip < 64)      { va = w_attn[cm * CIN_ + ip + 3];  vb = w1[cm * CIN_ + ip + 3]; }
                else if (ip < 67) { va = w_attn[cm * CIN_ + ip - 64]; vb = w1[cm * CIN_ + ip - 64]; }
                a[j] = f2bf(va); bq[j] = f2bf(vb);
            }
            wa_f[ks] = a; w1_f[ks] = bq;
        }
        #pragma unroll
        for (int ks = 0; ks < 2; ++ks) {
            short8v a;
            #pragma unroll
            for (int j = 0; j < 8; ++j)
                a[j] = f2bf(w2[cm * 64 + ks * 32 + quad * 8 + j]);
            w2_f[ks] = a;
        }
    }

    const int crow = mb * 16 + quad * 4;          // C/D row base (channel)
    const float4 bav = *(const float4*)&b_attn[crow];
    const float4 b1v = *(const float4*)&b1[crow];
    const float4 b2v = *(const float4*)&b2[crow];
    const int cf = t >> 2, ksf = t & 3;           // FFN mapping
    const float bf1v = bf1[cf];
    const float bf2v = bf2[cf];

    // zero the fj pad region i'=[72,104) once (i'=[67,72) rewritten each iter)
    for (int e = t; e < 512; e += 256) {
        const int col = e >> 2, c4 = e & 3;
        *(uint4*)&s_fj[col * SFJ + 72 + c4 * 8] = make_uint4(0u, 0u, 0u, 0u);
    }

    const int pt00 = blockIdx.x * (PTS * ITERS);
    for (int itn = 0; itn < ITERS; ++itn) {
        const int pt0 = pt00 + itn * PTS;
        const int b = pt0 >> 12;

        // ---- gather: 2 threads per column ----
        {
            const int col = t >> 1, h = t & 1;
            const int j = idx[pt0 * K_ + col];
            const uint4* src = (const uint4*)&ftb[((size_t)(b * N_ + j)) * 64 + h * 32];
            uint4* dst = (uint4*)&s_fj[col * SFJ + h * 32];
            dst[0] = src[0]; dst[1] = src[1]; dst[2] = src[2]; dst[3] = src[3];
            if (h) {
                const int n = (pt0 + (col >> 5)) & (N_ - 1);
                const float* pb = p + (size_t)b * N_ * 3;
                short8v dp = {};
                dp[0] = f2bf(pb[j * 3 + 0] - pb[n * 3 + 0]);
                dp[1] = f2bf(pb[j * 3 + 1] - pb[n * 3 + 1]);
                dp[2] = f2bf(pb[j * 3 + 2] - pb[n * 3 + 2]);
                *(short8v*)&s_fj[col * SFJ + 64] = dp;   // i' 64..71 (dp + zeros)
            }
        }
        __syncthreads();   // bar1: fj ready

        // ---- attn + conv1 MFMAs (shared B-frags); y1 -> LDS ----
        floatx4 accA[8];
        #pragma unroll
        for (int nt = 0; nt < 8; ++nt) {
            const short* bp = &s_fj[(nt * 16 + l15) * SFJ + quad * 8];
            const short8v fb0 = *(const short8v*)(bp);
            const short8v fb1 = *(const short8v*)(bp + 32);
            const short8v fb2 = *(const short8v*)(bp + 64);
            floatx4 a = {0.f, 0.f, 0.f, 0.f};
            a = __builtin_amdgcn_mfma_f32_16x16x32_bf16(wa_f[0], fb0, a, 0, 0, 0);
            a = __builtin_amdgcn_mfma_f32_16x16x32_bf16(wa_f[1], fb1, a, 0, 0, 0);
            a = __builtin_amdgcn_mfma_f32_16x16x32_bf16(wa_f[2], fb2, a, 0, 0, 0);
            accA[nt] = a;
            floatx4 y = {0.f, 0.f, 0.f, 0.f};
            y = __builtin_amdgcn_mfma_f32_16x16x32_bf16(w1_f[0], fb0, y, 0, 0, 0);
            y = __builtin_amdgcn_mfma_f32_16x16x32_bf16(w1_f[1], fb1, y, 0, 0, 0);
            y = __builtin_amdgcn_mfma_f32_16x16x32_bf16(w1_f[2], fb2, y, 0, 0, 0);
            short4v yp;
            yp[0] = f2bf(fmaxf(y[0] + b1v.x, 0.f));
            yp[1] = f2bf(fmaxf(y[1] + b1v.y, 0.f));
            yp[2] = f2bf(fmaxf(y[2] + b1v.z, 0.f));
            yp[3] = f2bf(fmaxf(y[3] + b1v.w, 0.f));
            *(short4v*)&s_y1[(nt * 16 + l15) * SY1 + crow] = yp;
        }
        __syncthreads();   // bar2: y1 ready

        // ---- conv2 MFMAs ----
        floatx4 accX[8];
        #pragma unroll
        for (int nt = 0; nt < 8; ++nt) {
            const short* bp = &s_y1[(nt * 16 + l15) * SY1 + quad * 8];
            const short8v yb0 = *(const short8v*)(bp);
            const short8v yb1 = *(const short8v*)(bp + 32);
            floatx4 x = {0.f, 0.f, 0.f, 0.f};
            x = __builtin_amdgcn_mfma_f32_16x16x32_bf16(w2_f[0], yb0, x, 0, 0, 0);
            x = __builtin_amdgcn_mfma_f32_16x16x32_bf16(w2_f[1], yb1, x, 0, 0, 0);
            accX[nt] = x;
        }

        // ---- softmax over K=32 (tiles 2pi, 2pi+1; 16-lane butterflies) ----
        #pragma unroll
        for (int pi = 0; pi < PTS; ++pi) {
            const int n = (pt0 + pi) & (N_ - 1);
            float fo[4];
            #pragma unroll
            for (int r = 0; r < 4; ++r) {
                const float ba = (r == 0) ? bav.x : (r == 1) ? bav.y : (r == 2) ? bav.z : bav.w;
                const float bx = (r == 0) ? b2v.x : (r == 1) ? b2v.y : (r == 2) ? b2v.z : b2v.w;
                const float va = accA[2 * pi][r] + ba;
                const float vb = accA[2 * pi + 1][r] + ba;
                float m = fmaxf(va, vb);
                m = fmaxf(m, __shfl_xor(m, 1));
                m = fmaxf(m, __shfl_xor(m, 2));
                m = fmaxf(m, __shfl_xor(m, 4));
                m = fmaxf(m, __shfl_xor(m, 8));
                const float e0 = __expf(va - m);
                const float e1 = __expf(vb - m);
                float se = e0 + e1;
                float sw = e0 * (accX[2 * pi][r] + bx) + e1 * (accX[2 * pi + 1][r] + bx);
                se += __shfl_xor(se, 1); sw += __shfl_xor(sw, 1);
                se += __shfl_xor(se, 2); sw += __shfl_xor(sw, 2);
                se += __shfl_xor(se, 4); sw += __shfl_xor(sw, 4);
                se += __shfl_xor(se, 8); sw += __shfl_xor(sw, 8);
                const float fres = f[((size_t)(b * 64 + crow + r)) * N_ + n];
                fo[r] = fmaxf(sw / se + fres, 0.f);
            }
            if (l15 == 0)
                *(float4*)&s_vec[pi * 64 + crow] = make_float4(fo[0], fo[1], fo[2], fo[3]);
        }
        __syncthreads();   // bar3: fout ready

        // ---- FFN layer 1 (c = t>>2, ks = t&3) ----
        float hv[PTS];
        #pragma unroll
        for (int pi = 0; pi < PTS; ++pi) {
            const float4* wr = (const float4*)&wf1[cf * 64 + ksf * 16];
            const float4* vr = (const float4*)&s_vec[pi * 64 + ksf * 16];
            float acc = 0.f;
            #pragma unroll
            for (int ii = 0; ii < 4; ++ii) {
                const float4 w = wr[ii];
                const float4 v = vr[ii];
                acc += w.x * v.x + w.y * v.y + w.z * v.z + w.w * v.w;
            }
            acc += __shfl_xor(acc, 1);
            acc += __shfl_xor(acc, 2);
            hv[pi] = fmaxf(acc + bf1v, 0.f);
        }
        #pragma unroll
        for (int pi = 0; pi < PTS; ++pi)
            if (ksf == 0) s_h[pi * 64 + cf] = hv[pi];
        __syncthreads();   // bar4: h ready

        // ---- FFN layer 2 + residual + relu ----
        #pragma unroll
        for (int pi = 0; pi < PTS; ++pi) {
            const float4* wr = (const float4*)&wf2[cf * 64 + ksf * 16];
            const float4* vr = (const float4*)&s_h[pi * 64 + ksf * 16];
            float acc = 0.f;
            #pragma unroll
            for (int ii = 0; ii < 4; ++ii) {
                const float4 w = wr[ii];
                const float4 v = vr[ii];
                acc += w.x * v.x + w.y * v.y + w.z * v.z + w.w * v.w;
            }
            acc += __shfl_xor(acc, 1);
            acc += __shfl_xor(acc, 2);
            if (ksf == 0) {
                const int n = (pt0 + pi) & (N_ - 1);
                out[((size_t)(b * 64 + cf)) * N_ + n] =
                    fmaxf(acc + bf2v + s_vec[pi * 64 + cf], 0.f);
            }
        }
        // no trailing barrier needed: next gather's s_fj writes are separated
        // from this iter's s_fj reads by bar2..bar4; s_vec/s_h rewrites are
        // separated by next iter's bar1/bar2/bar3.
    }
}

extern "C" void kernel_launch(void* const* d_in, const int* in_sizes, int n_in,
                              void* d_out, int out_size, void* d_ws, size_t ws_size,
                              hipStream_t stream)
{
    const float* p      = (const float*)d_in[0];
    const float* f      = (const float*)d_in[1];
    const float* w_attn = (const float*)d_in[2];
    const float* b_attn = (const float*)d_in[3];
    const float* w1     = (const float*)d_in[4];
    const float* b1     = (const float*)d_in[5];
    const float* w2     = (const float*)d_in[6];
    const float* b2     = (const float*)d_in[7];
    const float* wf1    = (const float*)d_in[8];
    const float* bf1    = (const float*)d_in[9];
    const float* wf2    = (const float*)d_in[10];
    const float* bf2    = (const float*)d_in[11];
    float* out = (float*)d_out;

    int* idx = (int*)d_ws;                                   // 4 MB
    unsigned short* ftb = (unsigned short*)((char*)d_ws + (size_t)B_ * N_ * K_ * 4);  // 4 MB

    // Output 0: p passthrough
    hipMemcpyAsync(out, p, (size_t)B_ * N_ * 3 * sizeof(float),
                   hipMemcpyDeviceToDevice, stream);

    transpose_f_kernel<<<B_ * (N_ / 64), 256, 0, stream>>>(f, ftb);
    ball_query_kernel<<<(B_ * N_) / 4, 256, 0, stream>>>(p, idx);
    lpa_mfma_kernel<<<(B_ * N_) / (PTS * ITERS), 256, 0, stream>>>(
        p, f, ftb, w_attn, b_attn, w1, b1, w2, b2, wf1, bf1, wf2, bf2,
        idx, out + (size_t)B_ * N_ * 3);
}

// Round 3
// 264.841 us; speedup vs baseline: 3.1622x; 1.2033x over previous
//
#include <hip/hip_runtime.h>

#define B_ 8
#define N_ 4096
#define K_ 32
#define C_ 64
#define CIN_ 67
#define R2_ 0.0225f

#define SFJ 104   // s_fj row stride in shorts (208 B: 16B-aligned, 2-way banks)
#define SY1 72    // s_y1 row stride in shorts (144 B)
#define SFB 72    // s_vecbf / s_hbf row stride in shorts
#define PTS 4     // points per block-iteration
#define ITERS 4   // iterations per block

typedef short short8v __attribute__((ext_vector_type(8)));
typedef short short4v __attribute__((ext_vector_type(4)));
typedef float floatx4 __attribute__((ext_vector_type(4)));

__device__ __forceinline__ short f2bf(float x) {
    unsigned u = __float_as_uint(x);
    u += 0x7fffu + ((u >> 16) & 1u);       // round-to-nearest-even
    return (short)(u >> 16);
}

// ---------------------------------------------------------------------------
// Prep: f[b][c][n] -> ftb[b][n][c] (bf16), p passthrough -> out, and packed
// p4[b][n] = (x,y,z,|p|^2). sq uses the same contract-off expression as the
// R1/R2-validated in-kernel computation (bit-identical boundary decisions).
// ---------------------------------------------------------------------------
__global__ __launch_bounds__(256) void prep_kernel(
    const float* __restrict__ p, const float* __restrict__ f,
    unsigned short* __restrict__ ftb, float4* __restrict__ p4,
    float* __restrict__ pout)
{
#pragma clang fp contract(off)
    __shared__ short tile[64 * 72];
    const int t = threadIdx.x;
    const int b = blockIdx.x >> 6;
    const int n0 = (blockIdx.x & 63) * 64;
    const int nn4 = t & 15, ch = t >> 4;
    for (int cc = 0; cc < 4; ++cc) {
        const int c = cc * 16 + ch;
        const float4 v = *(const float4*)&f[((size_t)(b * 64 + c)) * N_ + n0 + nn4 * 4];
        tile[(nn4 * 4 + 0) * 72 + c] = f2bf(v.x);
        tile[(nn4 * 4 + 1) * 72 + c] = f2bf(v.y);
        tile[(nn4 * 4 + 2) * 72 + c] = f2bf(v.z);
        tile[(nn4 * 4 + 3) * 72 + c] = f2bf(v.w);
    }
    if (t < 48) {   // p passthrough (192 floats per block, 16B-aligned)
        const size_t base = ((size_t)(b * N_ + n0)) * 3;
        ((float4*)(pout + base))[t] = ((const float4*)(p + base))[t];
    }
    if (t < 64) {   // packed p4
        const int n = n0 + t;
        const float x = p[((size_t)(b * N_ + n)) * 3 + 0];
        const float y = p[((size_t)(b * N_ + n)) * 3 + 1];
        const float z = p[((size_t)(b * N_ + n)) * 3 + 2];
        const float sq = (x * x + y * y) + z * z;
        p4[(size_t)b * N_ + n] = make_float4(x, y, z, sq);
    }
    __syncthreads();
    const int nn = t >> 2, cb = (t & 3) * 16;
    uint4* dst = (uint4*)&ftb[((size_t)(b * N_ + n0 + nn)) * 64 + cb];
    const uint4* src = (const uint4*)&tile[nn * 72 + cb];
    dst[0] = src[0];
    dst[1] = src[1];
}

// ---------------------------------------------------------------------------
// Ball query: one wave per query, 128 candidates per loop iteration using
// packed p4 (1 dwordx4 load/candidate). Same d2 expression as R2 (validated).
// idx stored as ushort (N=4096 < 65536).
// ---------------------------------------------------------------------------
__global__ __launch_bounds__(256) void ball_query_kernel(
    const float4* __restrict__ p4, unsigned short* __restrict__ idx)
{
#pragma clang fp contract(off)
    const int lane = threadIdx.x & 63;
    const int q = (blockIdx.x * blockDim.x + threadIdx.x) >> 6;
    const int b = q >> 12;
    const int n = q & (N_ - 1);
    const float4* pb = p4 + (size_t)b * N_;
    const float4 Q = pb[n];
    unsigned short* out = idx + (size_t)q * K_;
    int count = 0;
    int first = -1;
    for (int base = 0; base < N_; base += 128) {
        const float4 A  = pb[base + lane];
        const float4 Bv = pb[base + 64 + lane];
        const float d2a = (Q.w + A.w)  - 2.0f * ((Q.x * A.x  + Q.y * A.y)  + Q.z * A.z);
        const float d2b = (Q.w + Bv.w) - 2.0f * ((Q.x * Bv.x + Q.y * Bv.y) + Q.z * Bv.z);
        const bool wa = d2a <= R2_;
        const bool wb = d2b <= R2_;
        const unsigned long long m0 = __ballot(wa);
        const unsigned long long m1 = __ballot(wb);
        if (m0 | m1) {
            if (first < 0)
                first = m0 ? (base + __builtin_ctzll(m0))
                           : (base + 64 + __builtin_ctzll(m1));
            const int c0 = __popcll(m0);
            const unsigned long long below = (1ull << lane) - 1ull;
            if (wa) {
                const int pos = count + __popcll(m0 & below);
                if (pos < K_) out[pos] = (unsigned short)(base + lane);
            }
            if (wb) {
                const int pos = count + c0 + __popcll(m1 & below);
                if (pos < K_) out[pos] = (unsigned short)(base + 64 + lane);
            }
            count += c0 + __popcll(m1);
            if (count >= K_) break;
        }
    }
    for (int pos = count + lane; pos < K_; pos += 64) out[pos] = (unsigned short)first;
}

// ---------------------------------------------------------------------------
// Fused MFMA kernel. Block = 4 waves; wave mb owns channels [mb*16,mb*16+16).
// Per iter: 4 points = 8 N-tiles. attn/conv1/conv2 + FFN1/FFN2 all MFMA;
// only softmax + packing on VALU. Softmax without max-sub (|attn| <~ 2.5).
// ---------------------------------------------------------------------------
__global__ __launch_bounds__(256, 3) void lpa_mfma_kernel(
    const float4* __restrict__ p4, const float* __restrict__ f,
    const unsigned short* __restrict__ ftb,
    const float* __restrict__ w_attn, const float* __restrict__ b_attn,
    const float* __restrict__ w1, const float* __restrict__ b1,
    const float* __restrict__ w2, const float* __restrict__ b2,
    const float* __restrict__ wf1, const float* __restrict__ bf1,
    const float* __restrict__ wf2, const float* __restrict__ bf2,
    const unsigned short* __restrict__ idx, float* __restrict__ out)
{
    __shared__ __align__(16) short s_fj[128 * SFJ];   // 26624 B
    __shared__ __align__(16) short s_y1[128 * SY1];   // 18432 B
    __shared__ __align__(16) short s_fbuf[2 * 16 * SFB]; // vecbf + hbf, 4608 B
    __shared__ float s_vec[PTS * 64];                 // fp32 identity
    short* s_vecbf = s_fbuf;
    short* s_hbf   = s_fbuf + 16 * SFB;

    const int t = threadIdx.x;
    const int lane = t & 63;
    const int mb = t >> 6;
    const int l15 = lane & 15;
    const int quad = lane >> 4;

    // ---- weight A-fragments in registers (once per block) ----
    short8v wa_f[3], w1_f[3], w2_f[2], wf1_f[2], wf2_f[2];
    {
        const int cm = mb * 16 + l15;
        #pragma unroll
        for (int ks = 0; ks < 3; ++ks) {
            short8v a, bq;
            #pragma unroll
            for (int j = 0; j < 8; ++j) {
                const int ip = ks * 32 + quad * 8 + j;   // permuted i'
                float va = 0.0f, vb = 0.0f;
                if (ip < 64)      { va = w_attn[cm * CIN_ + ip + 3];  vb = w1[cm * CIN_ + ip + 3]; }
                else if (ip < 67) { va = w_attn[cm * CIN_ + ip - 64]; vb = w1[cm * CIN_ + ip - 64]; }
                a[j] = f2bf(va); bq[j] = f2bf(vb);
            }
            wa_f[ks] = a; w1_f[ks] = bq;
        }
        #pragma unroll
        for (int ks = 0; ks < 2; ++ks) {
            short8v a, bq, cq;
            #pragma unroll
            for (int j = 0; j < 8; ++j) {
                const int kk = ks * 32 + quad * 8 + j;
                a[j]  = f2bf(w2[cm * 64 + kk]);
                bq[j] = f2bf(wf1[cm * 64 + kk]);
                cq[j] = f2bf(wf2[cm * 64 + kk]);
            }
            w2_f[ks] = a; wf1_f[ks] = bq; wf2_f[ks] = cq;
        }
    }

    const int crow = mb * 16 + quad * 4;          // C/D row base (channel)
    const float4 bav  = *(const float4*)&b_attn[crow];
    const float4 b1v  = *(const float4*)&b1[crow];
    const float4 b2v  = *(const float4*)&b2[crow];
    const float4 bf1v = *(const float4*)&bf1[crow];
    const float4 bf2v = *(const float4*)&bf2[crow];

    // zero fj pad region i'=[72,104) and the ffn staging buffers
    for (int e = t; e < 512; e += 256) {
        const int col = e >> 2, c4 = e & 3;
        *(uint4*)&s_fj[col * SFJ + 72 + c4 * 8] = make_uint4(0u, 0u, 0u, 0u);
    }
    for (int e = t; e < 1152; e += 256) ((unsigned*)s_fbuf)[e] = 0u;

    const int pt00 = blockIdx.x * (PTS * ITERS);
    for (int itn = 0; itn < ITERS; ++itn) {
        const int pt0 = pt00 + itn * PTS;
        const int b = pt0 >> 12;

        // ---- gather: 2 threads per column ----
        {
            const int col = t >> 1, h = t & 1;
            const int j = idx[pt0 * K_ + col];
            const uint4* src = (const uint4*)&ftb[((size_t)(b * N_ + j)) * 64 + h * 32];
            uint4* dst = (uint4*)&s_fj[col * SFJ + h * 32];
            dst[0] = src[0]; dst[1] = src[1]; dst[2] = src[2]; dst[3] = src[3];
            if (h) {
                const int n = (pt0 + (col >> 5)) & (N_ - 1);
                const float4 Pj = p4[(size_t)b * N_ + j];
                const float4 Pn = p4[(size_t)b * N_ + n];
                short8v dp = {};
                dp[0] = f2bf(Pj.x - Pn.x);
                dp[1] = f2bf(Pj.y - Pn.y);
                dp[2] = f2bf(Pj.z - Pn.z);
                *(short8v*)&s_fj[col * SFJ + 64] = dp;   // i' 64..71 (dp + zeros)
            }
        }
        __syncthreads();   // bar1: fj ready

        // ---- attn + conv1 MFMAs (shared B-frags); y1 -> LDS ----
        floatx4 accA[8];
        #pragma unroll
        for (int nt = 0; nt < 8; ++nt) {
            const short* bp = &s_fj[(nt * 16 + l15) * SFJ + quad * 8];
            const short8v fb0 = *(const short8v*)(bp);
            const short8v fb1 = *(const short8v*)(bp + 32);
            const short8v fb2 = *(const short8v*)(bp + 64);
            floatx4 a = {0.f, 0.f, 0.f, 0.f};
            a = __builtin_amdgcn_mfma_f32_16x16x32_bf16(wa_f[0], fb0, a, 0, 0, 0);
            a = __builtin_amdgcn_mfma_f32_16x16x32_bf16(wa_f[1], fb1, a, 0, 0, 0);
            a = __builtin_amdgcn_mfma_f32_16x16x32_bf16(wa_f[2], fb2, a, 0, 0, 0);
            accA[nt] = a;
            floatx4 y = {0.f, 0.f, 0.f, 0.f};
            y = __builtin_amdgcn_mfma_f32_16x16x32_bf16(w1_f[0], fb0, y, 0, 0, 0);
            y = __builtin_amdgcn_mfma_f32_16x16x32_bf16(w1_f[1], fb1, y, 0, 0, 0);
            y = __builtin_amdgcn_mfma_f32_16x16x32_bf16(w1_f[2], fb2, y, 0, 0, 0);
            short4v yp;
            yp[0] = f2bf(fmaxf(y[0] + b1v.x, 0.f));
            yp[1] = f2bf(fmaxf(y[1] + b1v.y, 0.f));
            yp[2] = f2bf(fmaxf(y[2] + b1v.z, 0.f));
            yp[3] = f2bf(fmaxf(y[3] + b1v.w, 0.f));
            *(short4v*)&s_y1[(nt * 16 + l15) * SY1 + crow] = yp;
        }
        __syncthreads();   // bar2: y1 ready

        // ---- conv2 MFMAs ----
        floatx4 accX[8];
        #pragma unroll
        for (int nt = 0; nt < 8; ++nt) {
            const short* bp = &s_y1[(nt * 16 + l15) * SY1 + quad * 8];
            const short8v yb0 = *(const short8v*)(bp);
            const short8v yb1 = *(const short8v*)(bp + 32);
            floatx4 x = {0.f, 0.f, 0.f, 0.f};
            x = __builtin_amdgcn_mfma_f32_16x16x32_bf16(w2_f[0], yb0, x, 0, 0, 0);
            x = __builtin_amdgcn_mfma_f32_16x16x32_bf16(w2_f[1], yb1, x, 0, 0, 0);
            accX[nt] = x;
        }

        // ---- softmax over K=32 (no max-sub; args bounded ~|2.5|) ----
        #pragma unroll
        for (int pi = 0; pi < PTS; ++pi) {
            const int n = (pt0 + pi) & (N_ - 1);
            float fo[4];
            #pragma unroll
            for (int r = 0; r < 4; ++r) {
                const float ba = (r == 0) ? bav.x : (r == 1) ? bav.y : (r == 2) ? bav.z : bav.w;
                const float bx = (r == 0) ? b2v.x : (r == 1) ? b2v.y : (r == 2) ? b2v.z : b2v.w;
                const float va = accA[2 * pi][r] + ba;
                const float vb = accA[2 * pi + 1][r] + ba;
                const float e0 = __expf(va);
                const float e1 = __expf(vb);
                float se = e0 + e1;
                float sw = e0 * (accX[2 * pi][r] + bx) + e1 * (accX[2 * pi + 1][r] + bx);
                se += __shfl_xor(se, 1); sw += __shfl_xor(sw, 1);
                se += __shfl_xor(se, 2); sw += __shfl_xor(sw, 2);
                se += __shfl_xor(se, 4); sw += __shfl_xor(sw, 4);
                se += __shfl_xor(se, 8); sw += __shfl_xor(sw, 8);
                const float fres = f[((size_t)(b * 64 + crow + r)) * N_ + n];
                fo[r] = fmaxf(sw / se + fres, 0.f);
            }
            if (l15 == 0) {
                *(float4*)&s_vec[pi * 64 + crow] = make_float4(fo[0], fo[1], fo[2], fo[3]);
                short4v fb;
                fb[0] = f2bf(fo[0]); fb[1] = f2bf(fo[1]);
                fb[2] = f2bf(fo[2]); fb[3] = f2bf(fo[3]);
                *(short4v*)&s_vecbf[pi * SFB + crow] = fb;
            }
        }
        __syncthreads();   // bar3: fout ready

        // ---- FFN layer 1 via MFMA: M=16 (wave ch), K=64, N=16 (4 used) ----
        {
            const short8v vb0 = *(const short8v*)&s_vecbf[l15 * SFB + quad * 8];
            const short8v vb1 = *(const short8v*)&s_vecbf[l15 * SFB + 32 + quad * 8];
            floatx4 d = {0.f, 0.f, 0.f, 0.f};
            d = __builtin_amdgcn_mfma_f32_16x16x32_bf16(wf1_f[0], vb0, d, 0, 0, 0);
            d = __builtin_amdgcn_mfma_f32_16x16x32_bf16(wf1_f[1], vb1, d, 0, 0, 0);
            if (l15 < PTS) {
                short4v hb;
                hb[0] = f2bf(fmaxf(d[0] + bf1v.x, 0.f));
                hb[1] = f2bf(fmaxf(d[1] + bf1v.y, 0.f));
                hb[2] = f2bf(fmaxf(d[2] + bf1v.z, 0.f));
                hb[3] = f2bf(fmaxf(d[3] + bf1v.w, 0.f));
                *(short4v*)&s_hbf[l15 * SFB + crow] = hb;
            }
        }
        __syncthreads();   // bar4: h ready

        // ---- FFN layer 2 via MFMA + residual + relu, store ----
        {
            const short8v hb0 = *(const short8v*)&s_hbf[l15 * SFB + quad * 8];
            const short8v hb1 = *(const short8v*)&s_hbf[l15 * SFB + 32 + quad * 8];
            floatx4 d = {0.f, 0.f, 0.f, 0.f};
            d = __builtin_amdgcn_mfma_f32_16x16x32_bf16(wf2_f[0], hb0, d, 0, 0, 0);
            d = __builtin_amdgcn_mfma_f32_16x16x32_bf16(wf2_f[1], hb1, d, 0, 0, 0);
            if (l15 < PTS) {
                const int n = (pt0 + l15) & (N_ - 1);
                out[((size_t)(b * 64 + crow + 0)) * N_ + n] =
                    fmaxf(d[0] + bf2v.x + s_vec[l15 * 64 + crow + 0], 0.f);
                out[((size_t)(b * 64 + crow + 1)) * N_ + n] =
                    fmaxf(d[1] + bf2v.y + s_vec[l15 * 64 + crow + 1], 0.f);
                out[((size_t)(b * 64 + crow + 2)) * N_ + n] =
                    fmaxf(d[2] + bf2v.z + s_vec[l15 * 64 + crow + 2], 0.f);
                out[((size_t)(b * 64 + crow + 3)) * N_ + n] =
                    fmaxf(d[3] + bf2v.w + s_vec[l15 * 64 + crow + 3], 0.f);
            }
        }
        // hazard audit: next gather's s_fj writes separated from this iter's
        // s_fj reads by bar2..bar4; s_vecbf rewrite (next softmax) is after
        // next bar2 > this FFN1 reads; s_hbf rewrite after next bar3 > this
        // FFN2 reads. No trailing barrier needed.
    }
}

extern "C" void kernel_launch(void* const* d_in, const int* in_sizes, int n_in,
                              void* d_out, int out_size, void* d_ws, size_t ws_size,
                              hipStream_t stream)
{
    const float* p      = (const float*)d_in[0];
    const float* f      = (const float*)d_in[1];
    const float* w_attn = (const float*)d_in[2];
    const float* b_attn = (const float*)d_in[3];
    const float* w1     = (const float*)d_in[4];
    const float* b1     = (const float*)d_in[5];
    const float* w2     = (const float*)d_in[6];
    const float* b2     = (const float*)d_in[7];
    const float* wf1    = (const float*)d_in[8];
    const float* bf1    = (const float*)d_in[9];
    const float* wf2    = (const float*)d_in[10];
    const float* bf2    = (const float*)d_in[11];
    float* out = (float*)d_out;

    unsigned short* idx = (unsigned short*)d_ws;                           // 2 MB
    unsigned short* ftb = (unsigned short*)((char*)d_ws + 2u * 1024 * 1024); // 4 MB
    float4* p4          = (float4*)((char*)d_ws + 6u * 1024 * 1024);       // 512 KB

    prep_kernel<<<B_ * (N_ / 64), 256, 0, stream>>>(p, f, ftb, p4, out);
    ball_query_kernel<<<(B_ * N_) / 4, 256, 0, stream>>>(p4, idx);
    lpa_mfma_kernel<<<(B_ * N_) / (PTS * ITERS), 256, 0, stream>>>(
        p4, f, ftb, w_attn, b_attn, w1, b1, w2, b2, wf1, bf1, wf2, bf2,
        idx, out + (size_t)B_ * N_ * 3);
}